// Round 6
// baseline (237.075 us; speedup 1.0000x reference)
//
#include <hip/hip_runtime.h>
#include <hip/hip_bf16.h>
#include <math.h>

// Problem constants
#define H   1024
#define Dd  200
#define Kc  8
#define Bb  8
#define Ll  4096
#define Mm  (Bb*Ll)  // 32768 rows

typedef __attribute__((ext_vector_type(8))) short short8;
typedef __attribute__((ext_vector_type(4))) float f32x4;

// ws layout (bytes)
#define OFF_W1T  0                           // bf16 [256][1024] = 524288 B
#define OFF_S    524288                      // f32 [Mm][8]     = 1048576 B
#define OFF_SEG  (OFF_S + Mm*Kc*4)           // f32 [8][16][8]  = 4096 B
#define OFF_PART (OFF_SEG + Bb*16*Kc*4)      // f32 [128]
#define WS_NEEDED (OFF_PART + 128*4)

#define GLOAD16(g, l) __builtin_amdgcn_global_load_lds( \
    (const __attribute__((address_space(1))) void*)(g),  \
    (__attribute__((address_space(3))) void*)(l), 16, 0, 0)

__device__ __forceinline__ unsigned short f2bf(float x){
  unsigned u = __float_as_uint(x);
  unsigned r = (u + 0x7FFFu + ((u >> 16) & 1u)) >> 16;   // RNE
  return (unsigned short)r;
}

union Uc { short8 s8; __hip_bfloat162 h2[4]; };

// ---------------- prep: W1 (fp32 [H][200]) -> W1T (bf16 [256][H], zero-pad)
// LDS transpose: coalesced-ish reads (prev version did stride-800B scatter).
__global__ __launch_bounds__(256) void prep_w1t(const float* __restrict__ W1,
                                                unsigned short* __restrict__ W1T){
  __shared__ unsigned short lt[64][72];   // [h][d], padded
  const int bd = blockIdx.x & 3;          // 4 d-tiles of 64
  const int bh = blockIdx.x >> 2;         // 16 h-tiles of 64
  const int d0 = bd * 64, h0 = bh * 64;
  const int t  = threadIdx.x;

  const int hr = t >> 2, dc = (t & 3) * 16;
  #pragma unroll
  for (int dd = 0; dd < 4; ++dd){
    const int d = d0 + dc + dd * 4;
    float x0 = 0.f, x1 = 0.f, x2 = 0.f, x3 = 0.f;
    if (d + 3 < Dd){
      const float4 v = *(const float4*)(W1 + (size_t)(h0 + hr) * Dd + d);
      x0 = v.x; x1 = v.y; x2 = v.z; x3 = v.w;
    } else {
      if (d + 0 < Dd) x0 = W1[(size_t)(h0 + hr) * Dd + d + 0];
      if (d + 1 < Dd) x1 = W1[(size_t)(h0 + hr) * Dd + d + 1];
      if (d + 2 < Dd) x2 = W1[(size_t)(h0 + hr) * Dd + d + 2];
      if (d + 3 < Dd) x3 = W1[(size_t)(h0 + hr) * Dd + d + 3];
    }
    ushort4 p; p.x = f2bf(x0); p.y = f2bf(x1); p.z = f2bf(x2); p.w = f2bf(x3);
    *(ushort4*)(&lt[hr][dc + dd * 4]) = p;
  }
  __syncthreads();

  const int dl = t >> 2, hc = (t & 3) * 16;
  #pragma unroll
  for (int j = 0; j < 4; ++j){
    ushort4 o;
    o.x = lt[hc + j * 4 + 0][dl];
    o.y = lt[hc + j * 4 + 1][dl];
    o.z = lt[hc + j * 4 + 2][dl];
    o.w = lt[hc + j * 4 + 3][dl];
    *(ushort4*)(W1T + (size_t)(d0 + dl) * H + h0 + hc + j * 4) = o;
  }
}

// ---------------- fused GEMM1 (bf16 MFMA) + tanh + GEMM2 + mean-scale -> s
//                  + per-segment channel sums (atomics) -> segs
// 512 thr = 8 waves: rgp = wid>>2 (32-row half of BM=64), team = wid&3
// (tile sets {0-3},{4-6},{7-9},{10-12}). Per wave: 2 row-groups x 3-4 tiles
// -> A-frag reused over tiles, B-frag over row-groups (reads/FLOP -31%).
// A: coalesced global -> cvt bf16 -> ds_write, XOR-swizzled (rule #21 pair).
// B: double-buffered global_load_lds, pre-swizzled source.
// Counted vmcnt(6) mid-loop, never 0 (T4). waves_per_eu(4,4): 128-VGPR
// budget (R3-R5's 64-VGPR squeeze serialized ds_read->MFMA; this is the fix).
__global__ __launch_bounds__(512) __attribute__((amdgpu_waves_per_eu(4, 4)))
void gemm_fused(const float* __restrict__ hidd,
                const unsigned short* __restrict__ W1T,
                const float* __restrict__ b1,
                const float* __restrict__ W2,
                const float* __restrict__ b2,
                float* __restrict__ sOut,
                float* __restrict__ segs){
  __shared__ char lA[8192];             // bf16 [64 rows][128 B], swizzled
  __shared__ char lB[2 * 32768];        // 2 buffers x [256 cols][128 B]
  char* lAc = lA;
  float* epart = (float*)lA;            // post-loop reuse: [8][2][4][4][8]
  float* lrow  = (float*)lB;            // post-loop reuse: [64]
  float* red2  = (float*)(lB + 256);    // post-loop reuse: [8][8]
#define EP(w, rg, g, r, k) ((((((w)*2+(rg))*4+(g))*4+(r))*8)+(k))

  const int tid  = threadIdx.x;
  const int lane = tid & 63;
  const int wid  = tid >> 6;
  const int lc   = lane & 15;
  const int lg   = lane >> 4;
  const int team = wid & 3;             // tile team
  const int rgp  = wid >> 2;            // row-pair: rows rgp*32 .. +31
  const int tBase = (team == 0) ? 0 : (team == 1) ? 4 : (team == 2) ? 7 : 10;
  const int tCnt  = (team == 0) ? 4 : 3;
  const long rowBase = (long)blockIdx.x * 64;

  // A staging: thread t -> row t>>3, k8 = t&7 (8 floats); coalesced global.
  const int arow = tid >> 3, ak8 = tid & 7;
  const float* ag = hidd + (size_t)(rowBase + arow) * H + ak8 * 8;
  const int awb = ((arow * 128 + ak8 * 16) ^ ((arow & 7) << 4));

  // B staging: wave wid owns cols wid*32..+31 (4 chunks x 8 cols);
  // source pre-swizzled so swizzled READS see correct data (rule #21).
  const int swz = (((lane & 7) ^ (lane >> 3)) & 7) * 16;
  const char* bsrcj[4];
  #pragma unroll
  for (int j = 0; j < 4; ++j){
    const int colj = wid * 32 + j * 8 + (lane >> 3);   // 0..255, W1T padded
    bsrcj[j] = (const char*)W1T + (size_t)colj * 2048 + swz;
  }

  // fragment read offsets
  int aoff[2][2], boff[4][2];
  #pragma unroll
  for (int rg = 0; rg < 2; ++rg){
    const int rowA = rgp * 32 + rg * 16 + lc;
    aoff[rg][0] = rowA * 128 + (((lg * 16)) ^ ((lc & 7) << 4));
    aoff[rg][1] = rowA * 128 + ((64 + lg * 16) ^ ((lc & 7) << 4));
  }
  #pragma unroll
  for (int tt = 0; tt < 4; ++tt){
    const int tEff = tBase + ((tt < tCnt) ? tt : 0);
    const int col  = tEff * 16 + lc;
    boff[tt][0] = col * 128 + (((lg * 16)) ^ ((lc & 7) << 4));
    boff[tt][1] = col * 128 + ((64 + lg * 16) ^ ((lc & 7) << 4));
  }

  // prologue: A(0) regs + B(0) gloads  (6 VMEM outstanding)
  float4 pf[2][2];
  pf[0][0] = *(const float4*)(ag);
  pf[0][1] = *(const float4*)(ag + 4);
  #pragma unroll
  for (int j = 0; j < 4; ++j)
    GLOAD16(bsrcj[j], &lB[wid * 4096 + j * 1024]);

  f32x4 acc[2][4];
  #pragma unroll
  for (int rg = 0; rg < 2; ++rg)
    #pragma unroll
    for (int tt = 0; tt < 4; ++tt) acc[rg][tt] = (f32x4){0.f, 0.f, 0.f, 0.f};
  float ms = 0.f;

#define GEMM_STEP(KT, CUR, NXT) do {                                           \
    if ((KT) < 15){                                                            \
      pf[NXT][0] = *(const float4*)(ag + ((KT) + 1) * 64);                     \
      pf[NXT][1] = *(const float4*)(ag + ((KT) + 1) * 64 + 4);                 \
      GLOAD16(bsrcj[0] + ((KT)+1)*128, &lB[(NXT)*32768 + wid*4096 + 0*1024]);  \
      GLOAD16(bsrcj[1] + ((KT)+1)*128, &lB[(NXT)*32768 + wid*4096 + 1*1024]);  \
      GLOAD16(bsrcj[2] + ((KT)+1)*128, &lB[(NXT)*32768 + wid*4096 + 2*1024]);  \
      GLOAD16(bsrcj[3] + ((KT)+1)*128, &lB[(NXT)*32768 + wid*4096 + 3*1024]);  \
      asm volatile("s_waitcnt vmcnt(6)" ::: "memory");                         \
    } else {                                                                   \
      asm volatile("s_waitcnt vmcnt(0)" ::: "memory");                         \
    }                                                                          \
    {                                                                          \
      const float4 a0 = pf[CUR][0], a1 = pf[CUR][1];                           \
      ms += a0.x + a0.y + a0.z + a0.w + a1.x + a1.y + a1.z + a1.w;             \
      Uc u;                                                                    \
      u.h2[0] = __float22bfloat162_rn(make_float2(a0.x, a0.y));                \
      u.h2[1] = __float22bfloat162_rn(make_float2(a0.z, a0.w));                \
      u.h2[2] = __float22bfloat162_rn(make_float2(a1.x, a1.y));                \
      u.h2[3] = __float22bfloat162_rn(make_float2(a1.z, a1.w));                \
      *(short8*)(lAc + awb) = u.s8;                                            \
    }                                                                          \
    asm volatile("s_waitcnt lgkmcnt(0)" ::: "memory");                         \
    __builtin_amdgcn_s_barrier();                                              \
    __builtin_amdgcn_sched_barrier(0);                                         \
    {                                                                          \
      const char* bb = &lB[(CUR) * 32768];                                     \
      _Pragma("unroll")                                                        \
      for (int h = 0; h < 2; ++h){                                             \
        const short8 aF0 = *(const short8*)(lAc + aoff[0][h]);                 \
        const short8 aF1 = *(const short8*)(lAc + aoff[1][h]);                 \
        _Pragma("unroll")                                                      \
        for (int tt = 0; tt < 4; ++tt){                                        \
          if (tt < tCnt){                                                      \
            const short8 bF = *(const short8*)(bb + boff[tt][h]);              \
            acc[0][tt] = __builtin_amdgcn_mfma_f32_16x16x32_bf16(aF0, bF, acc[0][tt], 0, 0, 0); \
            acc[1][tt] = __builtin_amdgcn_mfma_f32_16x16x32_bf16(aF1, bF, acc[1][tt], 0, 0, 0); \
          }                                                                    \
        }                                                                      \
      }                                                                        \
    }                                                                          \
    if ((KT) < 15){                                                            \
      __builtin_amdgcn_sched_barrier(0);                                       \
      __builtin_amdgcn_s_barrier();                                            \
      __builtin_amdgcn_sched_barrier(0);                                       \
    }                                                                          \
  } while (0)

  for (int m = 0; m < 8; ++m){
    const int kt0 = m * 2;
    GEMM_STEP(kt0, 0, 1);
    GEMM_STEP(kt0 + 1, 1, 0);
  }
#undef GEMM_STEP

  __syncthreads();   // all lA/lB readers done; safe to reuse as epart/lrow

  // row means: reduce over the 8 lanes sharing a row (ak8)
  ms += __shfl_xor(ms, 1); ms += __shfl_xor(ms, 2); ms += __shfl_xor(ms, 4);
  if ((tid & 7) == 0) lrow[tid >> 3] = ms * (1.0f / 1024.0f);

  // epilogue: tanh + GEMM2 (in-register) + butterfly over lc, per row-group
  #pragma unroll
  for (int rg = 0; rg < 2; ++rg){
    float part[4][Kc];
    #pragma unroll
    for (int r = 0; r < 4; ++r)
      #pragma unroll
      for (int k = 0; k < Kc; ++k) part[r][k] = 0.f;

    #pragma unroll
    for (int tt = 0; tt < 4; ++tt){
      if (tt < tCnt){
        const int col = (tBase + tt) * 16 + lc;
        float b1v = 0.f;
        float w2v[Kc];
        if (col < Dd){
          b1v = b1[col];
          const float4 wa = *(const float4*)(W2 + col * Kc);
          const float4 wb = *(const float4*)(W2 + col * Kc + 4);
          w2v[0] = wa.x; w2v[1] = wa.y; w2v[2] = wa.z; w2v[3] = wa.w;
          w2v[4] = wb.x; w2v[5] = wb.y; w2v[6] = wb.z; w2v[7] = wb.w;
        } else {
          #pragma unroll
          for (int k = 0; k < Kc; ++k) w2v[k] = 0.f;
        }
        #pragma unroll
        for (int r = 0; r < 4; ++r){
          const float a = tanhf(acc[rg][tt][r] + b1v);
          #pragma unroll
          for (int k = 0; k < Kc; ++k) part[r][k] = fmaf(a, w2v[k], part[r][k]);
        }
      }
    }
    #pragma unroll
    for (int m = 1; m < 16; m <<= 1){
      #pragma unroll
      for (int r = 0; r < 4; ++r)
        #pragma unroll
        for (int k = 0; k < Kc; ++k)
          part[r][k] += __shfl_xor(part[r][k], m);
    }
    if (lc == 0){
      #pragma unroll
      for (int r = 0; r < 4; ++r)
        #pragma unroll
        for (int k = 0; k < Kc; ++k)
          epart[EP(wid, rg, lg, r, k)] = part[r][k];
    }
  }
  __syncthreads();

  // combine 4 teams, add b2, scale by row mean, store; then segment sums
  {
    const int row2 = tid >> 3, k = tid & 7;
    const int rgp2 = row2 >> 5, rg2 = (row2 >> 4) & 1;
    const int lg2 = (row2 >> 2) & 3, r2 = row2 & 3;
    float v = 0.f;
    #pragma unroll
    for (int tm = 0; tm < 4; ++tm)
      v += epart[EP(rgp2 * 4 + tm, rg2, lg2, r2, k)];
    const float sv = (v + b2[k]) * lrow[row2];
    sOut[(size_t)(rowBase + row2) * Kc + k] = sv;

    // segment channel sums: reduce 64 rows, 8 atomics per block
    float x = sv;
    x += __shfl_xor(x, 8); x += __shfl_xor(x, 16); x += __shfl_xor(x, 32);
    if (lane < 8) red2[wid * 8 + lane] = x;   // lane==k for lanes 0..7
  }
  __syncthreads();
  if (tid < 8){
    float t = 0.f;
    #pragma unroll
    for (int w = 0; w < 8; ++w) t += red2[w * 8 + tid];
    atomicAdd(segs + (rowBase >> 8) * 8 + tid, t);
  }
#undef EP
}

// ---------------- scan + det + softmax + log_softmax + pick -> partial loss
__global__ __launch_bounds__(256) void scan_loss(const float* __restrict__ s,
                                                 const float* __restrict__ segs,
                                                 const int* __restrict__ ptypes,
                                                 const int* __restrict__ labels,
                                                 float* __restrict__ partial){
  int b   = blockIdx.x >> 4;
  int seg = blockIdx.x & 15;
  int tid = threadIdx.x, lane = tid & 63, wid = tid >> 6;
  int l = seg * 256 + tid;

  float carry[8], T[8];
  #pragma unroll
  for (int k = 0; k < 8; ++k){ carry[k] = 0.f; T[k] = 0.f; }
  for (int ss = 0; ss < 16; ++ss){
    #pragma unroll
    for (int k = 0; k < 8; ++k){
      float x = segs[(b * 16 + ss) * 8 + k];
      T[k] += x;
      if (ss < seg) carry[k] += x;
    }
  }

  const float4* sp = (const float4*)(s + ((long)(b * Ll + l)) * Kc);
  float4 v0 = sp[0], v1 = sp[1];
  float sv[8] = {v0.x, v0.y, v0.z, v0.w, v1.x, v1.y, v1.z, v1.w};
  float P[8];
  #pragma unroll
  for (int k = 0; k < 8; ++k) P[k] = sv[k];

  #pragma unroll
  for (int st = 1; st < 64; st <<= 1){
    #pragma unroll
    for (int k = 0; k < 8; ++k){
      float u = __shfl_up(P[k], st);
      if (lane >= st) P[k] += u;
    }
  }
  __shared__ float wsum[4][8];
  if (lane == 63){
    #pragma unroll
    for (int k = 0; k < 8; ++k) wsum[wid][k] = P[k];
  }
  __syncthreads();
  for (int w = 0; w < wid; ++w){
    #pragma unroll
    for (int k = 0; k < 8; ++k) P[k] += wsum[w][k];
  }
  #pragma unroll
  for (int k = 0; k < 8; ++k) P[k] += carry[k];

  int pt = ptypes[b];
  float det[8];
  if (pt == 0){
    float inv = 1.0f / (float)(l + 1);
    #pragma unroll
    for (int k = 0; k < 8; ++k) det[k] = P[k] * inv;
  } else if (pt == 1){
    float inv = 1.0f / (float)(Ll - l);
    #pragma unroll
    for (int k = 0; k < 8; ++k) det[k] = (T[k] - P[k] + sv[k]) * inv;
  } else {
    #pragma unroll
    for (int k = 0; k < 8; ++k) det[k] = sv[k];
  }

  float mx = det[0];
  #pragma unroll
  for (int k = 1; k < 8; ++k) mx = fmaxf(mx, det[k]);
  float e[8], Z = 0.f;
  #pragma unroll
  for (int k = 0; k < 8; ++k){ e[k] = expf(det[k] - mx); Z += e[k]; }
  float invZ = 1.0f / Z;
  float p[8];
  #pragma unroll
  for (int k = 0; k < 8; ++k) p[k] = e[k] * invZ;
  float mx2 = p[0];
  #pragma unroll
  for (int k = 1; k < 8; ++k) mx2 = fmaxf(mx2, p[k]);
  float Z2 = 0.f;
  #pragma unroll
  for (int k = 0; k < 8; ++k) Z2 += expf(p[k] - mx2);
  float lse = logf(Z2) + mx2;

  int lab = labels[b * Ll + l];
  float picked = 0.f;
  #pragma unroll
  for (int k = 0; k < 8; ++k) picked = (lab == k) ? (p[k] - lse) : picked;

  float a = picked;
  a += __shfl_xor(a, 1);  a += __shfl_xor(a, 2);  a += __shfl_xor(a, 4);
  a += __shfl_xor(a, 8);  a += __shfl_xor(a, 16); a += __shfl_xor(a, 32);
  __shared__ float red[4];
  if (lane == 0) red[wid] = a;
  __syncthreads();
  if (tid == 0){
    partial[blockIdx.x] = red[0] + red[1] + red[2] + red[3];
  }
}

// ---------------- final: out[b] = -sum(partial[b*16 .. +15]) / L
__global__ __launch_bounds__(128) void final_loss(const float* __restrict__ partial,
                                                  float* __restrict__ out){
  int tid = threadIdx.x;  // 0..127 -> b = tid>>4
  float v = partial[tid];
  v += __shfl_xor(v, 1); v += __shfl_xor(v, 2);
  v += __shfl_xor(v, 4); v += __shfl_xor(v, 8);
  if ((tid & 15) == 0) out[tid >> 4] = -v * (1.0f / (float)Ll);
}

extern "C" void kernel_launch(void* const* d_in, const int* in_sizes, int n_in,
                              void* d_out, int out_size, void* d_ws, size_t ws_size,
                              hipStream_t stream){
  const float* hidd  = (const float*)d_in[0];
  const float* W1    = (const float*)d_in[1];
  const float* b1    = (const float*)d_in[2];
  const float* W2    = (const float*)d_in[3];
  const float* b2    = (const float*)d_in[4];
  const int* ptypes  = (const int*)d_in[5];
  const int* labels  = (const int*)d_in[6];
  float* out = (float*)d_out;
  char* ws = (char*)d_ws;
  if (ws_size < (size_t)WS_NEEDED) return;

  unsigned short* W1T = (unsigned short*)(ws + OFF_W1T);
  float* s       = (float*)(ws + OFF_S);
  float* segs    = (float*)(ws + OFF_SEG);
  float* partial = (float*)(ws + OFF_PART);

  prep_w1t<<<64, 256, 0, stream>>>(W1, W1T);
  hipMemsetAsync(segs, 0, Bb * 16 * Kc * sizeof(float), stream);
  gemm_fused<<<Mm / 64, 512, 0, stream>>>(hidd, W1T, b1, W2, b2, s, segs);
  scan_loss<<<Bb * 16, 256, 0, stream>>>(s, segs, ptypes, labels, partial);
  final_loss<<<1, 128, 0, stream>>>(partial, out);
}